// Round 23
// baseline (229.213 us; speedup 1.0000x reference)
//
#include <hip/hip_runtime.h>

// SAGEDense: h=relu(x@W1+b1); hn=mean_agg(h,src,dst); h2=relu(h@Ws+hn@Wn+b); out=relu(h2@W2+b2)
// GEMMs: M=100000, N=K=128, bf16 MFMA fp32-accum. GEMM2+GEMM3 fused.
// Aggregation: 2-level pow2 binning -> per-bucket LDS counting-sort + fp8 register gather.
// R23: gemm1 A-fragments converted in-register from direct global loads (no x staging);
// epilogue packs through a 16KB half-tile -> LDS 32->16KB, 6 blocks/CU.

typedef __bf16 bf16x8 __attribute__((ext_vector_type(8)));
typedef float f32x4 __attribute__((ext_vector_type(4)));
typedef float f32x2 __attribute__((ext_vector_type(2)));

#define D 128
#define SRC_BITS 17      // src < 2^17
#define OCT_SH 14        // octant = d >> 14 (0..6 for M=100000)
#define OCT_CAP 270336   // per-octant edge capacity
#define BCAP 1536        // per-bucket edge capacity (mean 1024 + 16 sigma)
#define BINCHUNK 4096    // edges per bin8 block (391 chunks — R16/R18 A/B optimum)

__device__ __forceinline__ unsigned short f2bf(float f){
  unsigned int u = __float_as_uint(f);
  u += 0x7FFF + ((u >> 16) & 1);           // RNE
  return (unsigned short)(u >> 16);
}

// All 4 weights in one launch: [k][n] fp32 -> [n][k] bf16
__global__ void prep_w_all(const float* __restrict__ Wa, const float* __restrict__ Wb,
                           const float* __restrict__ Wc, const float* __restrict__ Wd,
                           unsigned short* __restrict__ Ta, unsigned short* __restrict__ Tb,
                           unsigned short* __restrict__ Tc, unsigned short* __restrict__ Td){
  int which = blockIdx.x >> 7;
  int k = blockIdx.x & 127;
  int n = threadIdx.x;
  const float* W = (which == 0) ? Wa : (which == 1) ? Wb : (which == 2) ? Wc : Wd;
  unsigned short* T = (which == 0) ? Ta : (which == 1) ? Tb : (which == 2) ? Tc : Td;
  T[n * D + k] = f2bf(W[k * D + n]);
}

// ---------------- level 1: ballot-ranked octant binning ----------------
__launch_bounds__(256)
__global__ void bin8(const int* __restrict__ esrc, const int* __restrict__ edst,
                     int* __restrict__ ofill, unsigned* __restrict__ eoct, int E){
  __shared__ int lcnt[8], lbase[8], lrank[8];
  const int t = threadIdx.x;
  const int lane = t & 63;
  if (t < 8){ lcnt[t] = 0; lrank[t] = 0; }
  __syncthreads();
  const int base = blockIdx.x * BINCHUNK;
  const int lim = min(base + BINCHUNK, E);

  int myc = 0;
  for (int i0 = base + (t >> 6) * 64; i0 < lim; i0 += 256){
    int i = i0 + lane;
    int o = (i < lim) ? (edst[i] >> OCT_SH) : 8;
    #pragma unroll
    for (int k = 0; k < 8; k++){
      unsigned long long bk = __ballot(o == k);
      if (lane == k) myc += (int)__popcll(bk);
    }
  }
  if (lane < 8 && myc) atomicAdd(&lcnt[lane], myc);
  __syncthreads();
  if (t < 8) lbase[t] = atomicAdd(&ofill[t * 16], lcnt[t]);
  __syncthreads();

  for (int i0 = base + (t >> 6) * 64; i0 < lim; i0 += 256){
    int i = i0 + lane;
    bool valid = i < lim;
    int s = 0, o = 8, dloc = 0;
    if (valid){
      int d = edst[i];
      s = esrc[i];
      o = d >> OCT_SH;
      dloc = d & ((1 << OCT_SH) - 1);
    }
    int rank = 0, wcnt = 0;
    #pragma unroll
    for (int k = 0; k < 8; k++){
      unsigned long long bk = __ballot(o == k);
      if (o == k) rank = (int)__popcll(bk & ((1ull << lane) - 1));
      if (lane == k) wcnt = (int)__popcll(bk);
    }
    int wv = 0;
    if (lane < 8) wv = atomicAdd(&lrank[lane], wcnt);
    int mybase = __shfl(wv, o & 7);
    if (valid){
      int p = lbase[o] + mybase + rank;
      if (p < OCT_CAP)
        eoct[(size_t)o * OCT_CAP + p] = (unsigned)s | ((unsigned)dloc << SRC_BITS);
    }
  }
}

// ---------------- fused gemm1 || bin_bucket, 16KB LDS ----------------
__launch_bounds__(256, 6)
__global__ void gemm1_bucket(const float* __restrict__ A,
                             const unsigned short* __restrict__ Wt,
                             const float* __restrict__ bias,
                             unsigned short* __restrict__ hout,
                             unsigned char* __restrict__ h8out,
                             const unsigned* __restrict__ eoct, const int* __restrict__ ofill,
                             int* __restrict__ bfill, unsigned* __restrict__ ebkt,
                             int M, int nblk, int nbchunk)
{
  __shared__ unsigned short As[64 * 128];   // 16KB (epilogue half-tile / bucket counters)
  const int t = threadIdx.x;
  const int lane = t & 63;
  const int bid = blockIdx.x;
  const int g = bid / 7, r = bid % 7;

  if (r >= 3){
    // ---------------- bin_bucket role (bucket = d>>6, XCD-pinned by octant) ----------------
    const int c = g * 4 + (r - 3);
    if (c >= nbchunk) return;
    const int o = c & 7;
    const int chunk = c >> 3;
    const int n = min(ofill[o * 16], OCT_CAP);
    const int base = chunk * 2048;
    if (base >= n) return;
    const int lim = min(base + 2048, n);
    const unsigned* lst = eoct + (size_t)o * OCT_CAP;
    int* lcnt  = (int*)As;          // [256]
    int* lbase = (int*)As + 256;    // [256]
    int* lpos  = (int*)As + 512;    // [256]
    lcnt[t] = 0;
    __syncthreads();
    for (int i = base + t; i < lim; i += 256){
      int dloc = (int)(lst[i] >> SRC_BITS);
      atomicAdd(&lcnt[dloc >> 6], 1);       // 256 buckets of 64 nodes per octant
    }
    __syncthreads();
    if (lcnt[t] > 0) lbase[t] = atomicAdd(&bfill[((o << 8) + t) * 16], lcnt[t]);
    lpos[t] = 0;
    __syncthreads();
    for (int i = base + t; i < lim; i += 256){
      unsigned w = lst[i];
      int dloc = (int)(w >> SRC_BITS);
      int bk = dloc >> 6;
      int rr = atomicAdd(&lpos[bk], 1);
      int p = lbase[bk] + rr;
      unsigned v = (w & ((1u << SRC_BITS) - 1)) | ((unsigned)(dloc & 63) << SRC_BITS);
      if (p < BCAP) ebkt[(size_t)((o << 8) + bk) * BCAP + p] = v;
    }
    return;
  }

  // ---------------- gemm1 role: h = relu(x @ W1 + b1) ----------------
  // A-fragments converted in-register from direct global loads (no LDS staging;
  // each x row re-read 2x from L2, HBM traffic unchanged).
  const int tile = g * 3 + r;
  if (tile >= nblk) return;
  const int wave = t >> 6;
  const int rowBase = tile * 128;

  const int wr = (wave >> 1) * 64;
  const int wc = (wave & 1) * 64;
  const int fr = lane & 15;
  const int kg = lane >> 4;

  f32x4 zero = {0.f, 0.f, 0.f, 0.f};
  f32x4 acc[4][4];
  #pragma unroll
  for (int i = 0; i < 4; i++)
    #pragma unroll
    for (int j = 0; j < 4; j++) acc[i][j] = zero;

  #pragma unroll
  for (int ks = 0; ks < 4; ks++){
    const int cof = ks * 32 + kg * 8;        // float col offset of this lane's k-slice
    bf16x8 a[4], b[4];
    #pragma unroll
    for (int mi = 0; mi < 4; mi++){
      int row = rowBase + wr + mi * 16 + fr;
      if (row >= M) row = M - 1;
      const float* src = A + (size_t)row * D + cof;
      float4 v0 = *(const float4*)src;
      float4 v1 = *(const float4*)(src + 4);
      uint4 o;
      o.x = (unsigned)f2bf(v0.x) | ((unsigned)f2bf(v0.y) << 16);
      o.y = (unsigned)f2bf(v0.z) | ((unsigned)f2bf(v0.w) << 16);
      o.z = (unsigned)f2bf(v1.x) | ((unsigned)f2bf(v1.y) << 16);
      o.w = (unsigned)f2bf(v1.z) | ((unsigned)f2bf(v1.w) << 16);
      a[mi] = __builtin_bit_cast(bf16x8, o);
    }
    #pragma unroll
    for (int ni = 0; ni < 4; ni++){
      int row = wc + ni * 16 + fr;
      b[ni] = __builtin_bit_cast(bf16x8, *(const uint4*)((const char*)Wt + row * 256 + cof * 2));  // global, L1-hot
    }
    #pragma unroll
    for (int mi = 0; mi < 4; mi++)
      #pragma unroll
      for (int ni = 0; ni < 4; ni++)
        acc[mi][ni] = __builtin_amdgcn_mfma_f32_16x16x32_bf16(a[mi], b[ni], acc[mi][ni], 0, 0, 0);
  }

  // epilogue: two 64-row halves through the 16KB As tile, packed stores
  const int myhalf = wave >> 1;                 // wr == myhalf*64
  #pragma unroll
  for (int half = 0; half < 2; half++){
    if (myhalf == half){
      #pragma unroll
      for (int ni = 0; ni < 4; ni++){
        int col = wc + ni * 16 + fr;
        float bv = bias[col];
        #pragma unroll
        for (int mi = 0; mi < 4; mi++)
          #pragma unroll
          for (int j = 0; j < 4; j++){
            int row = mi * 16 + kg * 4 + j;   // 0..63 local
            float v = fmaxf(acc[mi][ni][j] + bv, 0.0f);
            *(unsigned short*)((char*)As + row * 256 + ((col * 2) ^ ((row & 7) << 4))) = f2bf(v);
          }
      }
    }
    __syncthreads();
    #pragma unroll
    for (int i = 0; i < 4; i++){
      int idx = t + i * 256;
      int row = idx >> 4;                     // 64 rows x 16 chunks of 16B
      int inb = (idx & 15) << 4;
      int gg = rowBase + half * 64 + row;
      if (gg < M){
        uint4 v = *(const uint4*)((const char*)As + row * 256 + (inb ^ ((row & 7) << 4)));
        *(uint4*)((char*)hout + (size_t)gg * 256 + inb) = v;
        float f0 = __uint_as_float(v.x << 16), f1 = __uint_as_float(v.x & 0xffff0000u);
        float f2 = __uint_as_float(v.y << 16), f3 = __uint_as_float(v.y & 0xffff0000u);
        float f4 = __uint_as_float(v.z << 16), f5 = __uint_as_float(v.z & 0xffff0000u);
        float f6 = __uint_as_float(v.w << 16), f7 = __uint_as_float(v.w & 0xffff0000u);
        int lo = 0, hi = 0;
        lo = __builtin_amdgcn_cvt_pk_fp8_f32(f0, f1, lo, false);
        lo = __builtin_amdgcn_cvt_pk_fp8_f32(f2, f3, lo, true);
        hi = __builtin_amdgcn_cvt_pk_fp8_f32(f4, f5, hi, false);
        hi = __builtin_amdgcn_cvt_pk_fp8_f32(f6, f7, hi, true);
        uint2 o8 = make_uint2((unsigned)lo, (unsigned)hi);
        *(uint2*)(h8out + (size_t)gg * 128 + (inb >> 1)) = o8;
      }
    }
    __syncthreads();
  }
}

// ---------------- fused counting-sort + fp8 gather-mean -> fp8 hn, 512 thr / bucket ----------------
__launch_bounds__(512)
__global__ void gather_sorted(const unsigned char* __restrict__ h8,
                              const unsigned* __restrict__ ebkt,
                              const int* __restrict__ bfill,
                              unsigned char* __restrict__ hn8, int M){
  __shared__ unsigned earr[BCAP];         // 6KB, holds src*128 byte offsets
  __shared__ int lcnt[64], lbeg[64], lpos[64];
  const int b = blockIdx.x;               // global bucket = d >> 6
  const int t = threadIdx.x;
  const int lane = t & 63;
  const int wave = t >> 6;                // 0..7
  const int half = lane >> 5;             // 0/1 = which edge of a pair
  const int li = lane & 31;               // dims 4li..4li+3
  const int nE = min(bfill[b * 16], BCAP);
  const int nodeBase = b << 6;
  const int nNodes = min(64, M - nodeBase);
  const unsigned* lst = ebkt + (size_t)b * BCAP;

  if (t < 64) lcnt[t] = 0;
  __syncthreads();
  for (int i = t; i < nE; i += 512)
    atomicAdd(&lcnt[lst[i] >> SRC_BITS], 1);
  __syncthreads();
  // single-wave inclusive shuffle scan over 64 counters
  if (wave == 0){
    int c = lcnt[lane];
    int x = c;
    #pragma unroll
    for (int d = 1; d < 64; d <<= 1){
      int v = __shfl_up(x, d);
      if (lane >= d) x += v;
    }
    lbeg[lane] = x;          // inclusive end
    lpos[lane] = x - c;      // exclusive start
  }
  __syncthreads();
  for (int i = t; i < nE; i += 512){
    unsigned w = lst[i];
    int k = (int)(w >> SRC_BITS);
    int p = atomicAdd(&lpos[k], 1);
    earr[p] = (w & ((1u << SRC_BITS) - 1)) << 7;   // byte offset (src*128)
  }
  __syncthreads();

  const int li4 = li * 4;
  for (int nI = wave; nI < nNodes; nI += 8){
    int deg = lcnt[nI];
    int end = lbeg[nI];
    int beg = end - deg;
    float a0 = 0.f, a1 = 0.f, a2 = 0.f, a3 = 0.f;
    int i = beg;
    // 16 edges per batch = 8 paired loads
    for (; i + 16 <= end; i += 16){
      unsigned pk[8];
      #pragma unroll
      for (int u = 0; u < 8; u++)
        pk[u] = *(const unsigned*)(h8 + earr[i + 2 * u + half] + li4);
      #pragma unroll
      for (int u = 0; u < 8; u++){
        f32x2 f01 = __builtin_amdgcn_cvt_pk_f32_fp8(pk[u], false);
        f32x2 f23 = __builtin_amdgcn_cvt_pk_f32_fp8(pk[u], true);
        a0 += f01[0]; a1 += f01[1]; a2 += f23[0]; a3 += f23[1];
      }
    }
    for (; i + 2 <= end; i += 2){
      unsigned v = *(const unsigned*)(h8 + earr[i + half] + li4);
      f32x2 f01 = __builtin_amdgcn_cvt_pk_f32_fp8(v, false);
      f32x2 f23 = __builtin_amdgcn_cvt_pk_f32_fp8(v, true);
      a0 += f01[0]; a1 += f01[1]; a2 += f23[0]; a3 += f23[1];
    }
    if (i < end && half == 0){   // odd tail (low half only)
      unsigned v = *(const unsigned*)(h8 + earr[i] + li4);
      f32x2 f01 = __builtin_amdgcn_cvt_pk_f32_fp8(v, false);
      f32x2 f23 = __builtin_amdgcn_cvt_pk_f32_fp8(v, true);
      a0 += f01[0]; a1 += f01[1]; a2 += f23[0]; a3 += f23[1];
    }
    // merge the two edge-halves
    a0 += __shfl_xor(a0, 32); a1 += __shfl_xor(a1, 32);
    a2 += __shfl_xor(a2, 32); a3 += __shfl_xor(a3, 32);
    if (half == 0){
      float inv = 1.0f / (float)max(deg, 1);
      int w8 = 0;
      w8 = __builtin_amdgcn_cvt_pk_fp8_f32(a0 * inv, a1 * inv, w8, false);
      w8 = __builtin_amdgcn_cvt_pk_fp8_f32(a2 * inv, a3 * inv, w8, true);
      *(unsigned*)(hn8 + (size_t)(nodeBase + nI) * D + li4) = (unsigned)w8;  // 32 lanes x 4B = 128B
    }
  }
}

// ---------------- fused SAGE combine + final layer, 32KB LDS ----------------
#define STAGE_BF16(A, dstLDS)                                              \
  _Pragma("unroll")                                                        \
  for (int i = 0; i < 8; i++){                                             \
    int idx = t + i * 256;                                                 \
    int row = idx >> 4;                                                    \
    int inb = (idx & 15) << 4;                                             \
    int g = rowBase + row; if (g >= M) g = M - 1;                          \
    uint4 v = *(const uint4*)((const char*)(A) + (size_t)g * 256 + inb);   \
    *(uint4*)((char*)(dstLDS) + row * 256 + (inb ^ ((row & 7) << 4))) = v; \
  }

__launch_bounds__(256, 4)
__global__ void gemm_fused(const unsigned short* __restrict__ h,
                           const unsigned short* __restrict__ Wst,
                           const unsigned char* __restrict__ hn8,
                           const unsigned short* __restrict__ Wnt,
                           const unsigned short* __restrict__ W2t,
                           const float* __restrict__ bsage,
                           const float* __restrict__ b2,
                           float* __restrict__ out, int M)
{
  __shared__ unsigned short As[128 * 128];   // 32KB only
  const int t = threadIdx.x;
  const int lane = t & 63;
  const int wave = t >> 6;
  const int rowBase = blockIdx.x * 128;

  const int wr = (wave >> 1) * 64;
  const int wc = (wave & 1) * 64;
  const int fr = lane & 15;
  const int kg = lane >> 4;

  f32x4 zero = {0.f, 0.f, 0.f, 0.f};
  f32x4 acc[4][4];
  #pragma unroll
  for (int i = 0; i < 4; i++)
    #pragma unroll
    for (int j = 0; j < 4; j++) acc[i][j] = zero;

  auto mma_pass = [&](const unsigned short* W){
    #pragma unroll
    for (int ks = 0; ks < 4; ks++){
      int kb = ks * 64 + kg * 16;
      bf16x8 a[4], b[4];
      #pragma unroll
      for (int mi = 0; mi < 4; mi++){
        int row = wr + mi * 16 + fr;
        a[mi] = __builtin_bit_cast(bf16x8, *(const uint4*)((const char*)As + row * 256 + (kb ^ ((row & 7) << 4))));
      }
      #pragma unroll
      for (int ni = 0; ni < 4; ni++){
        int row = wc + ni * 16 + fr;
        b[ni] = __builtin_bit_cast(bf16x8, *(const uint4*)((const char*)W + row * 256 + kb));  // global, L1-hot
      }
      #pragma unroll
      for (int mi = 0; mi < 4; mi++)
        #pragma unroll
        for (int ni = 0; ni < 4; ni++)
          acc[mi][ni] = __builtin_amdgcn_mfma_f32_16x16x32_bf16(a[mi], b[ni], acc[mi][ni], 0, 0, 0);
    }
  };

  // prefetch hn8 tile into registers (fp8, 8B/thread/iter; expanded to bf16 later)
  uint2 hreg[8];
  #pragma unroll
  for (int i = 0; i < 8; i++){
    int idx = t + i * 256;
    int row = idx >> 4;
    int inb = (idx & 15) << 4;
    int g = rowBase + row; if (g >= M) g = M - 1;
    hreg[i] = *(const uint2*)(hn8 + (size_t)g * D + (inb >> 1));
  }

  STAGE_BF16(h, As);
  __syncthreads();
  mma_pass(Wst);
  __syncthreads();

  // expand prefetched hn8 -> bf16 -> As
  #pragma unroll
  for (int i = 0; i < 8; i++){
    int idx = t + i * 256;
    int row = idx >> 4;
    int inb = (idx & 15) << 4;
    f32x2 p0 = __builtin_amdgcn_cvt_pk_f32_fp8(hreg[i].x, false);
    f32x2 p1 = __builtin_amdgcn_cvt_pk_f32_fp8(hreg[i].x, true);
    f32x2 p2 = __builtin_amdgcn_cvt_pk_f32_fp8(hreg[i].y, false);
    f32x2 p3 = __builtin_amdgcn_cvt_pk_f32_fp8(hreg[i].y, true);
    uint4 o;
    o.x = (unsigned)f2bf(p0[0]) | ((unsigned)f2bf(p0[1]) << 16);
    o.y = (unsigned)f2bf(p1[0]) | ((unsigned)f2bf(p1[1]) << 16);
    o.z = (unsigned)f2bf(p2[0]) | ((unsigned)f2bf(p2[1]) << 16);
    o.w = (unsigned)f2bf(p3[0]) | ((unsigned)f2bf(p3[1]) << 16);
    *(uint4*)((char*)As + row * 256 + (inb ^ ((row & 7) << 4))) = o;
  }
  __syncthreads();
  mma_pass(Wnt);
  __syncthreads();

  // h2 = relu(acc + bsage) -> As (bf16, swizzled); reset acc
  #pragma unroll
  for (int ni = 0; ni < 4; ni++){
    int col = wc + ni * 16 + fr;
    float bv = bsage[col];
    #pragma unroll
    for (int mi = 0; mi < 4; mi++)
      #pragma unroll
      for (int j = 0; j < 4; j++){
        int row = wr + mi * 16 + kg * 4 + j;
        unsigned short hv = f2bf(fmaxf(acc[mi][ni][j] + bv, 0.0f));
        *(unsigned short*)((char*)As + row * 256 + ((col * 2) ^ ((row & 7) << 4))) = hv;
        acc[mi][ni][j] = 0.f;
      }
  }
  __syncthreads();
  mma_pass(W2t);
  __syncthreads();   // As free after this

  // final epilogue: acc + b2, relu -> fp32 out via As in two 64-row halves (packed stores)
  const int myhalf = wave >> 1;
  #pragma unroll
  for (int half = 0; half < 2; half++){
    if (myhalf == half){
      #pragma unroll
      for (int ni = 0; ni < 4; ni++){
        int col = wc + ni * 16 + fr;
        float bv = b2[col];
        #pragma unroll
        for (int mi = 0; mi < 4; mi++)
          #pragma unroll
          for (int j = 0; j < 4; j++){
            int row = mi * 16 + kg * 4 + j;   // 0..63 local
            float v = fmaxf(acc[mi][ni][j] + bv, 0.0f);
            *(float*)((char*)As + row * 512 + ((col * 4) ^ ((row & 7) << 4))) = v;
          }
      }
    }
    __syncthreads();
    #pragma unroll
    for (int i = 0; i < 8; i++){
      int idx = t + i * 256;
      int row = idx >> 5;              // 64 rows x 32 chunks of 16B
      int inb = (idx & 31) << 4;
      int gg = rowBase + half * 64 + row;
      if (gg < M){
        uint4 v = *(const uint4*)((const char*)As + row * 512 + (inb ^ ((row & 7) << 4)));
        *(uint4*)((char*)out + (size_t)gg * 512 + inb) = v;
      }
    }
    __syncthreads();
  }
}

extern "C" void kernel_launch(void* const* d_in, const int* in_sizes, int n_in,
                              void* d_out, int out_size, void* d_ws, size_t ws_size,
                              hipStream_t stream)
{
  const float* x     = (const float*)d_in[0];
  const int*   esrc  = (const int*)d_in[1];
  const int*   edst  = (const int*)d_in[2];
  const float* W1    = (const float*)d_in[3];
  const float* b1    = (const float*)d_in[4];
  const float* Wself = (const float*)d_in[5];
  const float* Wneigh= (const float*)d_in[6];
  const float* bsage = (const float*)d_in[7];
  const float* W2    = (const float*)d_in[8];
  const float* b2    = (const float*)d_in[9];

  const int M = in_sizes[0] / D;   // 100000
  const int E = in_sizes[1];       // 1600000
  const int NBK = (M + 63) >> 6;   // 1563 64-node buckets

  // ---- workspace layout (~73 MB) ----
  char* ws = (char*)d_ws;
  unsigned short* W1t = (unsigned short*)(ws);
  unsigned short* Wst = (unsigned short*)(ws + 32768);
  unsigned short* Wnt = (unsigned short*)(ws + 65536);
  unsigned short* W2t = (unsigned short*)(ws + 98304);
  size_t hbytes = (size_t)M * D * 2;            // 25.6 MB
  unsigned short* h   = (unsigned short*)(ws + 131072);
  unsigned char*  hn8 = (unsigned char*)(ws + 131072 + hbytes);       // 12.8 MB fp8
  unsigned char*  h8  = (unsigned char*)(ws + 131072 + hbytes + (size_t)M * D);  // 12.8 MB fp8
  char* p = ws + 131072 + hbytes + 2 * (size_t)M * D;
  int* ofill = (int*)p;                  p += 8 * 16 * 4;            // 512B
  int* bfill = (int*)p;                  p += (size_t)2048 * 16 * 4; // 128KB
  unsigned* eoct = (unsigned*)p;         p += (size_t)8 * OCT_CAP * 4;   // 8.65 MB
  unsigned* ebkt = (unsigned*)p;         // 2048 * BCAP * 4 = 12.6 MB

  prep_w_all<<<4 * D, D, 0, stream>>>(W1, Wself, Wneigh, W2, W1t, Wst, Wnt, W2t);
  hipMemsetAsync(ofill, 0, 512 + (size_t)2048 * 16 * 4, stream);

  const int nblk = (M + 127) / 128;                  // 782 gemm tiles
  const int nchunk = (E + BINCHUNK - 1) / BINCHUNK;  // 391 bin8 chunks
  const int nbchunk = 8 * ((OCT_CAP + 2047) / 2048); // 1056 bucket chunks

  // level-1 octant binning (standalone, full occupancy)
  bin8<<<nchunk, 256, 0, stream>>>(esrc, edst, ofill, eoct, E);

  // h = relu(x@W1+b1) (bf16 + fp8 shadow)  ||  level-2 bucket binning (needs only eoct)
  {
    int ngroups = 264;   // 3*264=792 >= 782 gemm tiles; 4*264=1056 bucket chunks
    gemm1_bucket<<<7 * ngroups, 256, 0, stream>>>(x, W1t, b1, h, h8,
                                                  eoct, ofill, bfill, ebkt,
                                                  M, nblk, nbchunk);
  }

  // fused counting-sort + fp8 gather-mean -> fp8 hn
  gather_sorted<<<NBK, 512, 0, stream>>>(h8, ebkt, bfill, hn8, M);

  // out = relu( relu(h@Ws + hn@Wn + bsage) @ W2 + b2 )
  gemm_fused<<<nblk, 256, 0, stream>>>(h, Wst, hn8, Wnt, W2t, bsage, b2, (float*)d_out, M);
}

// Round 24
// 161.783 us; speedup vs baseline: 1.4168x; 1.4168x over previous
//
#include <hip/hip_runtime.h>

// SAGEDense: h=relu(x@W1+b1); hn=mean_agg(h,src,dst); h2=relu(h@Ws+hn@Wn+b); out=relu(h2@W2+b2)
// GEMMs: M=100000, N=K=128, bf16 MFMA fp32-accum. GEMM2+GEMM3 fused.
// Aggregation: 2-level pow2 binning -> per-bucket LDS counting-sort + fp8 register gather.
// R24 = revert to R22 (best: 164.5us). R23 lesson: removing LDS staging for in-register
// A-fragments fragments the global access (32B slices, 8x re-read) -> FETCH 3x. Staging
// removal is only free when each line is consumed whole by one wave.

typedef __bf16 bf16x8 __attribute__((ext_vector_type(8)));
typedef float f32x4 __attribute__((ext_vector_type(4)));
typedef float f32x2 __attribute__((ext_vector_type(2)));

#define D 128
#define SRC_BITS 17      // src < 2^17
#define OCT_SH 14        // octant = d >> 14 (0..6 for M=100000)
#define OCT_CAP 270336   // per-octant edge capacity
#define BCAP 1536        // per-bucket edge capacity (mean 1024 + 16 sigma)
#define BINCHUNK 4096    // edges per bin8 block (391 chunks — R16/R18 A/B optimum)

__device__ __forceinline__ unsigned short f2bf(float f){
  unsigned int u = __float_as_uint(f);
  u += 0x7FFF + ((u >> 16) & 1);           // RNE
  return (unsigned short)(u >> 16);
}

// All 4 weights in one launch: [k][n] fp32 -> [n][k] bf16
__global__ void prep_w_all(const float* __restrict__ Wa, const float* __restrict__ Wb,
                           const float* __restrict__ Wc, const float* __restrict__ Wd,
                           unsigned short* __restrict__ Ta, unsigned short* __restrict__ Tb,
                           unsigned short* __restrict__ Tc, unsigned short* __restrict__ Td){
  int which = blockIdx.x >> 7;
  int k = blockIdx.x & 127;
  int n = threadIdx.x;
  const float* W = (which == 0) ? Wa : (which == 1) ? Wb : (which == 2) ? Wc : Wd;
  unsigned short* T = (which == 0) ? Ta : (which == 1) ? Tb : (which == 2) ? Tc : Td;
  T[n * D + k] = f2bf(W[k * D + n]);
}

// ---------------- level 1: ballot-ranked octant binning ----------------
__launch_bounds__(256)
__global__ void bin8(const int* __restrict__ esrc, const int* __restrict__ edst,
                     int* __restrict__ ofill, unsigned* __restrict__ eoct, int E){
  __shared__ int lcnt[8], lbase[8], lrank[8];
  const int t = threadIdx.x;
  const int lane = t & 63;
  if (t < 8){ lcnt[t] = 0; lrank[t] = 0; }
  __syncthreads();
  const int base = blockIdx.x * BINCHUNK;
  const int lim = min(base + BINCHUNK, E);

  int myc = 0;
  for (int i0 = base + (t >> 6) * 64; i0 < lim; i0 += 256){
    int i = i0 + lane;
    int o = (i < lim) ? (edst[i] >> OCT_SH) : 8;
    #pragma unroll
    for (int k = 0; k < 8; k++){
      unsigned long long bk = __ballot(o == k);
      if (lane == k) myc += (int)__popcll(bk);
    }
  }
  if (lane < 8 && myc) atomicAdd(&lcnt[lane], myc);
  __syncthreads();
  if (t < 8) lbase[t] = atomicAdd(&ofill[t * 16], lcnt[t]);
  __syncthreads();

  for (int i0 = base + (t >> 6) * 64; i0 < lim; i0 += 256){
    int i = i0 + lane;
    bool valid = i < lim;
    int s = 0, o = 8, dloc = 0;
    if (valid){
      int d = edst[i];
      s = esrc[i];
      o = d >> OCT_SH;
      dloc = d & ((1 << OCT_SH) - 1);
    }
    int rank = 0, wcnt = 0;
    #pragma unroll
    for (int k = 0; k < 8; k++){
      unsigned long long bk = __ballot(o == k);
      if (o == k) rank = (int)__popcll(bk & ((1ull << lane) - 1));
      if (lane == k) wcnt = (int)__popcll(bk);
    }
    int wv = 0;
    if (lane < 8) wv = atomicAdd(&lrank[lane], wcnt);
    int mybase = __shfl(wv, o & 7);
    if (valid){
      int p = lbase[o] + mybase + rank;
      if (p < OCT_CAP)
        eoct[(size_t)o * OCT_CAP + p] = (unsigned)s | ((unsigned)dloc << SRC_BITS);
    }
  }
}

// ---------------- fused gemm1 || bin_bucket, 32KB LDS ----------------
__launch_bounds__(256, 4)
__global__ void gemm1_bucket(const float* __restrict__ A,
                             const unsigned short* __restrict__ Wt,
                             const float* __restrict__ bias,
                             unsigned short* __restrict__ hout,
                             unsigned char* __restrict__ h8out,
                             const unsigned* __restrict__ eoct, const int* __restrict__ ofill,
                             int* __restrict__ bfill, unsigned* __restrict__ ebkt,
                             int M, int nblk, int nbchunk)
{
  __shared__ unsigned short As[128 * 128];   // 32KB
  const int t = threadIdx.x;
  const int lane = t & 63;
  const int bid = blockIdx.x;
  const int g = bid / 7, r = bid % 7;

  if (r >= 3){
    // ---------------- bin_bucket role (bucket = d>>6, XCD-pinned by octant) ----------------
    const int c = g * 4 + (r - 3);
    if (c >= nbchunk) return;
    const int o = c & 7;
    const int chunk = c >> 3;
    const int n = min(ofill[o * 16], OCT_CAP);
    const int base = chunk * 2048;
    if (base >= n) return;
    const int lim = min(base + 2048, n);
    const unsigned* lst = eoct + (size_t)o * OCT_CAP;
    int* lcnt  = (int*)As;          // [256]
    int* lbase = (int*)As + 256;    // [256]
    int* lpos  = (int*)As + 512;    // [256]
    lcnt[t] = 0;
    __syncthreads();
    for (int i = base + t; i < lim; i += 256){
      int dloc = (int)(lst[i] >> SRC_BITS);
      atomicAdd(&lcnt[dloc >> 6], 1);       // 256 buckets of 64 nodes per octant
    }
    __syncthreads();
    if (lcnt[t] > 0) lbase[t] = atomicAdd(&bfill[((o << 8) + t) * 16], lcnt[t]);
    lpos[t] = 0;
    __syncthreads();
    for (int i = base + t; i < lim; i += 256){
      unsigned w = lst[i];
      int dloc = (int)(w >> SRC_BITS);
      int bk = dloc >> 6;
      int rr = atomicAdd(&lpos[bk], 1);
      int p = lbase[bk] + rr;
      unsigned v = (w & ((1u << SRC_BITS) - 1)) | ((unsigned)(dloc & 63) << SRC_BITS);
      if (p < BCAP) ebkt[(size_t)((o << 8) + bk) * BCAP + p] = v;
    }
    return;
  }

  // ---------------- gemm1 role: h = relu(x @ W1 + b1), dual bf16 + fp8 output ----------------
  const int tile = g * 3 + r;
  if (tile >= nblk) return;
  const int wave = t >> 6;
  const int rowBase = tile * 128;

  f32x4 zero = {0.f, 0.f, 0.f, 0.f};
  f32x4 acc[4][4];
  #pragma unroll
  for (int i = 0; i < 4; i++)
    #pragma unroll
    for (int j = 0; j < 4; j++) acc[i][j] = zero;

  #pragma unroll
  for (int i = 0; i < 8; i++){
    int idx = t + i * 256;
    int row = idx >> 4;
    int inb = (idx & 15) << 4;
    int gg = rowBase + row; if (gg >= M) gg = M - 1;
    const float* src = A + (size_t)gg * D + (inb >> 1);
    float4 v0 = *(const float4*)src;
    float4 v1 = *(const float4*)(src + 4);
    uint4 o;
    o.x = (unsigned)f2bf(v0.x) | ((unsigned)f2bf(v0.y) << 16);
    o.y = (unsigned)f2bf(v0.z) | ((unsigned)f2bf(v0.w) << 16);
    o.z = (unsigned)f2bf(v1.x) | ((unsigned)f2bf(v1.y) << 16);
    o.w = (unsigned)f2bf(v1.z) | ((unsigned)f2bf(v1.w) << 16);
    *(uint4*)((char*)As + row * 256 + (inb ^ ((row & 7) << 4))) = o;
  }
  __syncthreads();

  const int wr = (wave >> 1) * 64;
  const int wc = (wave & 1) * 64;
  const int fr = lane & 15;
  const int kg = lane >> 4;

  #pragma unroll
  for (int ks = 0; ks < 4; ks++){
    int kb = ks * 64 + kg * 16;
    bf16x8 a[4], b[4];
    #pragma unroll
    for (int mi = 0; mi < 4; mi++){
      int row = wr + mi * 16 + fr;
      a[mi] = __builtin_bit_cast(bf16x8, *(const uint4*)((const char*)As + row * 256 + (kb ^ ((row & 7) << 4))));
    }
    #pragma unroll
    for (int ni = 0; ni < 4; ni++){
      int row = wc + ni * 16 + fr;
      b[ni] = __builtin_bit_cast(bf16x8, *(const uint4*)((const char*)Wt + row * 256 + kb));  // global, L1-hot
    }
    #pragma unroll
    for (int mi = 0; mi < 4; mi++)
      #pragma unroll
      for (int ni = 0; ni < 4; ni++)
        acc[mi][ni] = __builtin_amdgcn_mfma_f32_16x16x32_bf16(a[mi], b[ni], acc[mi][ni], 0, 0, 0);
  }
  __syncthreads();   // all waves done reading As

  // epilogue: acc -> As (bf16, swizzled; <=2-way banks), then packed stores
  #pragma unroll
  for (int ni = 0; ni < 4; ni++){
    int col = wc + ni * 16 + fr;
    float bv = bias[col];
    #pragma unroll
    for (int mi = 0; mi < 4; mi++)
      #pragma unroll
      for (int j = 0; j < 4; j++){
        int row = wr + mi * 16 + kg * 4 + j;
        float v = fmaxf(acc[mi][ni][j] + bv, 0.0f);
        *(unsigned short*)((char*)As + row * 256 + ((col * 2) ^ ((row & 7) << 4))) = f2bf(v);
      }
  }
  __syncthreads();
  // coalesced uint4 stores of h; fp8 conversion from the same data -> uint2 stores
  #pragma unroll
  for (int i = 0; i < 8; i++){
    int idx = t + i * 256;
    int row = idx >> 4;
    int inb = (idx & 15) << 4;
    int gg = rowBase + row;
    if (gg < M){
      uint4 v = *(const uint4*)((const char*)As + row * 256 + (inb ^ ((row & 7) << 4)));
      *(uint4*)((char*)hout + (size_t)gg * 256 + inb) = v;
      float f0 = __uint_as_float(v.x << 16), f1 = __uint_as_float(v.x & 0xffff0000u);
      float f2 = __uint_as_float(v.y << 16), f3 = __uint_as_float(v.y & 0xffff0000u);
      float f4 = __uint_as_float(v.z << 16), f5 = __uint_as_float(v.z & 0xffff0000u);
      float f6 = __uint_as_float(v.w << 16), f7 = __uint_as_float(v.w & 0xffff0000u);
      int lo = 0, hi = 0;
      lo = __builtin_amdgcn_cvt_pk_fp8_f32(f0, f1, lo, false);
      lo = __builtin_amdgcn_cvt_pk_fp8_f32(f2, f3, lo, true);
      hi = __builtin_amdgcn_cvt_pk_fp8_f32(f4, f5, hi, false);
      hi = __builtin_amdgcn_cvt_pk_fp8_f32(f6, f7, hi, true);
      uint2 o8 = make_uint2((unsigned)lo, (unsigned)hi);
      *(uint2*)(h8out + (size_t)gg * 128 + (inb >> 1)) = o8;
    }
  }
}

// ---------------- fused counting-sort + fp8 gather-mean -> fp8 hn, 512 thr / bucket ----------------
__launch_bounds__(512)
__global__ void gather_sorted(const unsigned char* __restrict__ h8,
                              const unsigned* __restrict__ ebkt,
                              const int* __restrict__ bfill,
                              unsigned char* __restrict__ hn8, int M){
  __shared__ unsigned earr[BCAP];         // 6KB, holds src*128 byte offsets
  __shared__ int lcnt[64], lbeg[64], lpos[64];
  const int b = blockIdx.x;               // global bucket = d >> 6
  const int t = threadIdx.x;
  const int lane = t & 63;
  const int wave = t >> 6;                // 0..7
  const int half = lane >> 5;             // 0/1 = which edge of a pair
  const int li = lane & 31;               // dims 4li..4li+3
  const int nE = min(bfill[b * 16], BCAP);
  const int nodeBase = b << 6;
  const int nNodes = min(64, M - nodeBase);
  const unsigned* lst = ebkt + (size_t)b * BCAP;

  if (t < 64) lcnt[t] = 0;
  __syncthreads();
  for (int i = t; i < nE; i += 512)
    atomicAdd(&lcnt[lst[i] >> SRC_BITS], 1);
  __syncthreads();
  // single-wave inclusive shuffle scan over 64 counters
  if (wave == 0){
    int c = lcnt[lane];
    int x = c;
    #pragma unroll
    for (int d = 1; d < 64; d <<= 1){
      int v = __shfl_up(x, d);
      if (lane >= d) x += v;
    }
    lbeg[lane] = x;          // inclusive end
    lpos[lane] = x - c;      // exclusive start
  }
  __syncthreads();
  for (int i = t; i < nE; i += 512){
    unsigned w = lst[i];
    int k = (int)(w >> SRC_BITS);
    int p = atomicAdd(&lpos[k], 1);
    earr[p] = (w & ((1u << SRC_BITS) - 1)) << 7;   // byte offset (src*128)
  }
  __syncthreads();

  const int li4 = li * 4;
  for (int nI = wave; nI < nNodes; nI += 8){
    int deg = lcnt[nI];
    int end = lbeg[nI];
    int beg = end - deg;
    float a0 = 0.f, a1 = 0.f, a2 = 0.f, a3 = 0.f;
    int i = beg;
    // 16 edges per batch = 8 paired loads
    for (; i + 16 <= end; i += 16){
      unsigned pk[8];
      #pragma unroll
      for (int u = 0; u < 8; u++)
        pk[u] = *(const unsigned*)(h8 + earr[i + 2 * u + half] + li4);
      #pragma unroll
      for (int u = 0; u < 8; u++){
        f32x2 f01 = __builtin_amdgcn_cvt_pk_f32_fp8(pk[u], false);
        f32x2 f23 = __builtin_amdgcn_cvt_pk_f32_fp8(pk[u], true);
        a0 += f01[0]; a1 += f01[1]; a2 += f23[0]; a3 += f23[1];
      }
    }
    for (; i + 2 <= end; i += 2){
      unsigned v = *(const unsigned*)(h8 + earr[i + half] + li4);
      f32x2 f01 = __builtin_amdgcn_cvt_pk_f32_fp8(v, false);
      f32x2 f23 = __builtin_amdgcn_cvt_pk_f32_fp8(v, true);
      a0 += f01[0]; a1 += f01[1]; a2 += f23[0]; a3 += f23[1];
    }
    if (i < end && half == 0){   // odd tail (low half only)
      unsigned v = *(const unsigned*)(h8 + earr[i] + li4);
      f32x2 f01 = __builtin_amdgcn_cvt_pk_f32_fp8(v, false);
      f32x2 f23 = __builtin_amdgcn_cvt_pk_f32_fp8(v, true);
      a0 += f01[0]; a1 += f01[1]; a2 += f23[0]; a3 += f23[1];
    }
    // merge the two edge-halves
    a0 += __shfl_xor(a0, 32); a1 += __shfl_xor(a1, 32);
    a2 += __shfl_xor(a2, 32); a3 += __shfl_xor(a3, 32);
    if (half == 0){
      float inv = 1.0f / (float)max(deg, 1);
      int w8 = 0;
      w8 = __builtin_amdgcn_cvt_pk_fp8_f32(a0 * inv, a1 * inv, w8, false);
      w8 = __builtin_amdgcn_cvt_pk_fp8_f32(a2 * inv, a3 * inv, w8, true);
      *(unsigned*)(hn8 + (size_t)(nodeBase + nI) * D + li4) = (unsigned)w8;  // 32 lanes x 4B = 128B
    }
  }
}

// ---------------- fused SAGE combine + final layer, 32KB LDS ----------------
#define STAGE_BF16(A, dstLDS)                                              \
  _Pragma("unroll")                                                        \
  for (int i = 0; i < 8; i++){                                             \
    int idx = t + i * 256;                                                 \
    int row = idx >> 4;                                                    \
    int inb = (idx & 15) << 4;                                             \
    int g = rowBase + row; if (g >= M) g = M - 1;                          \
    uint4 v = *(const uint4*)((const char*)(A) + (size_t)g * 256 + inb);   \
    *(uint4*)((char*)(dstLDS) + row * 256 + (inb ^ ((row & 7) << 4))) = v; \
  }

__launch_bounds__(256, 4)
__global__ void gemm_fused(const unsigned short* __restrict__ h,
                           const unsigned short* __restrict__ Wst,
                           const unsigned char* __restrict__ hn8,
                           const unsigned short* __restrict__ Wnt,
                           const unsigned short* __restrict__ W2t,
                           const float* __restrict__ bsage,
                           const float* __restrict__ b2,
                           float* __restrict__ out, int M)
{
  __shared__ unsigned short As[128 * 128];   // 32KB only
  const int t = threadIdx.x;
  const int lane = t & 63;
  const int wave = t >> 6;
  const int rowBase = blockIdx.x * 128;

  const int wr = (wave >> 1) * 64;
  const int wc = (wave & 1) * 64;
  const int fr = lane & 15;
  const int kg = lane >> 4;

  f32x4 zero = {0.f, 0.f, 0.f, 0.f};
  f32x4 acc[4][4];
  #pragma unroll
  for (int i = 0; i < 4; i++)
    #pragma unroll
    for (int j = 0; j < 4; j++) acc[i][j] = zero;

  auto mma_pass = [&](const unsigned short* W){
    #pragma unroll
    for (int ks = 0; ks < 4; ks++){
      int kb = ks * 64 + kg * 16;
      bf16x8 a[4], b[4];
      #pragma unroll
      for (int mi = 0; mi < 4; mi++){
        int row = wr + mi * 16 + fr;
        a[mi] = __builtin_bit_cast(bf16x8, *(const uint4*)((const char*)As + row * 256 + (kb ^ ((row & 7) << 4))));
      }
      #pragma unroll
      for (int ni = 0; ni < 4; ni++){
        int row = wc + ni * 16 + fr;
        b[ni] = __builtin_bit_cast(bf16x8, *(const uint4*)((const char*)W + row * 256 + kb));  // global, L1-hot
      }
      #pragma unroll
      for (int mi = 0; mi < 4; mi++)
        #pragma unroll
        for (int ni = 0; ni < 4; ni++)
          acc[mi][ni] = __builtin_amdgcn_mfma_f32_16x16x32_bf16(a[mi], b[ni], acc[mi][ni], 0, 0, 0);
    }
  };

  // prefetch hn8 tile into registers (fp8, 8B/thread/iter; expanded to bf16 later)
  uint2 hreg[8];
  #pragma unroll
  for (int i = 0; i < 8; i++){
    int idx = t + i * 256;
    int row = idx >> 4;
    int inb = (idx & 15) << 4;
    int g = rowBase + row; if (g >= M) g = M - 1;
    hreg[i] = *(const uint2*)(hn8 + (size_t)g * D + (inb >> 1));
  }

  STAGE_BF16(h, As);
  __syncthreads();
  mma_pass(Wst);
  __syncthreads();

  // expand prefetched hn8 -> bf16 -> As
  #pragma unroll
  for (int i = 0; i < 8; i++){
    int idx = t + i * 256;
    int row = idx >> 4;
    int inb = (idx & 15) << 4;
    f32x2 p0 = __builtin_amdgcn_cvt_pk_f32_fp8(hreg[i].x, false);
    f32x2 p1 = __builtin_amdgcn_cvt_pk_f32_fp8(hreg[i].x, true);
    f32x2 p2 = __builtin_amdgcn_cvt_pk_f32_fp8(hreg[i].y, false);
    f32x2 p3 = __builtin_amdgcn_cvt_pk_f32_fp8(hreg[i].y, true);
    uint4 o;
    o.x = (unsigned)f2bf(p0[0]) | ((unsigned)f2bf(p0[1]) << 16);
    o.y = (unsigned)f2bf(p1[0]) | ((unsigned)f2bf(p1[1]) << 16);
    o.z = (unsigned)f2bf(p2[0]) | ((unsigned)f2bf(p2[1]) << 16);
    o.w = (unsigned)f2bf(p3[0]) | ((unsigned)f2bf(p3[1]) << 16);
    *(uint4*)((char*)As + row * 256 + (inb ^ ((row & 7) << 4))) = o;
  }
  __syncthreads();
  mma_pass(Wnt);
  __syncthreads();

  // h2 = relu(acc + bsage) -> As (bf16, swizzled); reset acc
  #pragma unroll
  for (int ni = 0; ni < 4; ni++){
    int col = wc + ni * 16 + fr;
    float bv = bsage[col];
    #pragma unroll
    for (int mi = 0; mi < 4; mi++)
      #pragma unroll
      for (int j = 0; j < 4; j++){
        int row = wr + mi * 16 + kg * 4 + j;
        unsigned short hv = f2bf(fmaxf(acc[mi][ni][j] + bv, 0.0f));
        *(unsigned short*)((char*)As + row * 256 + ((col * 2) ^ ((row & 7) << 4))) = hv;
        acc[mi][ni][j] = 0.f;
      }
  }
  __syncthreads();
  mma_pass(W2t);
  __syncthreads();   // As free after this

  // final epilogue: acc + b2, relu -> fp32 out via As in two 64-row halves (packed stores)
  const int myhalf = wave >> 1;
  #pragma unroll
  for (int half = 0; half < 2; half++){
    if (myhalf == half){
      #pragma unroll
      for (int ni = 0; ni < 4; ni++){
        int col = wc + ni * 16 + fr;
        float bv = b2[col];
        #pragma unroll
        for (int mi = 0; mi < 4; mi++)
          #pragma unroll
          for (int j = 0; j < 4; j++){
            int row = mi * 16 + kg * 4 + j;   // 0..63 local
            float v = fmaxf(acc[mi][ni][j] + bv, 0.0f);
            *(float*)((char*)As + row * 512 + ((col * 4) ^ ((row & 7) << 4))) = v;
          }
      }
    }
    __syncthreads();
    #pragma unroll
    for (int i = 0; i < 8; i++){
      int idx = t + i * 256;
      int row = idx >> 5;              // 64 rows x 32 chunks of 16B
      int inb = (idx & 31) << 4;
      int gg = rowBase + half * 64 + row;
      if (gg < M){
        uint4 v = *(const uint4*)((const char*)As + row * 512 + (inb ^ ((row & 7) << 4)));
        *(uint4*)((char*)out + (size_t)gg * 512 + inb) = v;
      }
    }
    __syncthreads();
  }
}

extern "C" void kernel_launch(void* const* d_in, const int* in_sizes, int n_in,
                              void* d_out, int out_size, void* d_ws, size_t ws_size,
                              hipStream_t stream)
{
  const float* x     = (const float*)d_in[0];
  const int*   esrc  = (const int*)d_in[1];
  const int*   edst  = (const int*)d_in[2];
  const float* W1    = (const float*)d_in[3];
  const float* b1    = (const float*)d_in[4];
  const float* Wself = (const float*)d_in[5];
  const float* Wneigh= (const float*)d_in[6];
  const float* bsage = (const float*)d_in[7];
  const float* W2    = (const float*)d_in[8];
  const float* b2    = (const float*)d_in[9];

  const int M = in_sizes[0] / D;   // 100000
  const int E = in_sizes[1];       // 1600000
  const int NBK = (M + 63) >> 6;   // 1563 64-node buckets

  // ---- workspace layout (~73 MB) ----
  char* ws = (char*)d_ws;
  unsigned short* W1t = (unsigned short*)(ws);
  unsigned short* Wst = (unsigned short*)(ws + 32768);
  unsigned short* Wnt = (unsigned short*)(ws + 65536);
  unsigned short* W2t = (unsigned short*)(ws + 98304);
  size_t hbytes = (size_t)M * D * 2;            // 25.6 MB
  unsigned short* h   = (unsigned short*)(ws + 131072);
  unsigned char*  hn8 = (unsigned char*)(ws + 131072 + hbytes);       // 12.8 MB fp8
  unsigned char*  h8  = (unsigned char*)(ws + 131072 + hbytes + (size_t)M * D);  // 12.8 MB fp8
  char* p = ws + 131072 + hbytes + 2 * (size_t)M * D;
  int* ofill = (int*)p;                  p += 8 * 16 * 4;            // 512B
  int* bfill = (int*)p;                  p += (size_t)2048 * 16 * 4; // 128KB
  unsigned* eoct = (unsigned*)p;         p += (size_t)8 * OCT_CAP * 4;   // 8.65 MB
  unsigned* ebkt = (unsigned*)p;         // 2048 * BCAP * 4 = 12.6 MB

  prep_w_all<<<4 * D, D, 0, stream>>>(W1, Wself, Wneigh, W2, W1t, Wst, Wnt, W2t);
  hipMemsetAsync(ofill, 0, 512 + (size_t)2048 * 16 * 4, stream);

  const int nblk = (M + 127) / 128;                  // 782 gemm tiles
  const int nchunk = (E + BINCHUNK - 1) / BINCHUNK;  // 391 bin8 chunks
  const int nbchunk = 8 * ((OCT_CAP + 2047) / 2048); // 1056 bucket chunks

  // level-1 octant binning (standalone, full occupancy)
  bin8<<<nchunk, 256, 0, stream>>>(esrc, edst, ofill, eoct, E);

  // h = relu(x@W1+b1) (bf16 + fp8 shadow)  ||  level-2 bucket binning (needs only eoct)
  {
    int ngroups = 264;   // 3*264=792 >= 782 gemm tiles; 4*264=1056 bucket chunks
    gemm1_bucket<<<7 * ngroups, 256, 0, stream>>>(x, W1t, b1, h, h8,
                                                  eoct, ofill, bfill, ebkt,
                                                  M, nblk, nbchunk);
  }

  // fused counting-sort + fp8 gather-mean -> fp8 hn
  gather_sorted<<<NBK, 512, 0, stream>>>(h8, ebkt, bfill, hn8, M);

  // out = relu( relu(h@Ws + hn@Wn + bsage) @ W2 + b2 )
  gemm_fused<<<nblk, 256, 0, stream>>>(h, Wst, hn8, Wnt, W2t, bsage, b2, (float*)d_out, M);
}